// Round 5
// baseline (392.325 us; speedup 1.0000x reference)
//
#include <hip/hip_runtime.h>
#include <hip/hip_bf16.h>

#define C_ 3
#define L_ 3
#define HB 38          // staged buffer rows/cols (32 + 2*3 halo)
#define WB 43          // padded LDS row stride (odd -> bank spread)
#define BUFSZ (C_*HB*WB)

// ws layout (floats)
#define WS_LDCONST 0
#define WS_W       8      // 243 folded conv weights
#define WS_CC      256    // 9 folded bias constants
#define WS_ALPHA   272    // 9
#define WS_IALPHA  288    // 9
#define WS_LDACC   1024   // B per-batch accumulators

// ---------------- kernel 1: zero accumulators, fold weights ----------------
__global__ void k_init(const float* __restrict__ ab,   // actnorm_bias (L,1,C,1,1)
                       const float* __restrict__ als,  // actnorm_log_scale
                       const float* __restrict__ K,    // (L,C,C,3,3)
                       const float* __restrict__ la,   // slog_log_alpha
                       float* __restrict__ ws, int B)
{
    int t = threadIdx.x;
    if (t < 8) ws[t] = 0.f;
    for (int i = t; i < B; i += 1024) ws[WS_LDACC + i] = 0.f;
    if (t < 243) {
        int li = t / 81; int rem = t % 81; int ic = (rem % 27) / 9;
        // conv(actnorm(h)) fold: W' = K * exp(ls_ic)
        ws[WS_W + t] = K[t] * __expf(als[li*3 + ic]);
    }
    if (t >= 256 && t < 265) {
        int i = t - 256; int li = i / 3, oc = i % 3;
        float s = 0.f;
        for (int ic = 0; ic < 3; ++ic) {
            float ks = 0.f;
            for (int k9 = 0; k9 < 9; ++k9) ks += K[((li*3+oc)*3+ic)*9 + k9];
            s += ab[li*3 + ic] * ks;
        }
        ws[WS_CC + i] = s;
    }
    if (t >= 272 && t < 281) {
        int i = t - 272;
        float a = __expf(la[i]);
        ws[WS_ALPHA + i]  = a;
        ws[WS_IALPHA + i] = 1.f / a;
    }
}

// ------------- kernel 2: data-independent logdet constant ------------------
// ldconst = sum_i [ n^2*sum(ls_i) + sum(cls_i) + sum_{u,v} log|det Kh_i(u,v)| ]
__global__ void k_logdet(const float* __restrict__ als,
                         const float* __restrict__ K,
                         const float* __restrict__ cls, // (L,1,C,N,N)
                         float* __restrict__ ws)
{
    __shared__ float sK[81];
    __shared__ float red[4];
    int li  = blockIdx.x >> 4;
    int sub = blockIdx.x & 15;
    int t = threadIdx.x;
    if (t < 81) sK[t] = K[li*81 + t];
    __syncthreads();
    float part = 0.f;
    {   // slice of sum(cls)
        const float* p = cls + li*(3*128*128) + sub*3072;
        for (int i = t; i < 3072; i += 256) part += p[i];
    }
    const float w0 = -(2.f * 3.14159265358979f / 128.f);
    for (int f = sub*1024 + t; f < sub*1024 + 1024; f += 256) {
        int u = f >> 7, v = f & 127;
        float su, cu, sv, cv;
        __sincosf(w0 * (float)u, &su, &cu);
        __sincosf(w0 * (float)v, &sv, &cv);
        float cu2 = cu*cu - su*su, su2 = 2.f*cu*su;   // e_u^2
        float cv2 = cv*cv - sv*sv, sv2 = 2.f*cv*sv;
        float evr[3] = {1.f, cv, cv2}, evi[3] = {0.f, sv, sv2};
        float eur[3] = {1.f, cu, cu2}, eui[3] = {0.f, su, su2};
        float Mr[3][3], Mi[3][3];
        #pragma unroll
        for (int o = 0; o < 3; ++o)
        #pragma unroll
        for (int i2 = 0; i2 < 3; ++i2) {
            float mr = 0.f, mi = 0.f;
            #pragma unroll
            for (int p = 0; p < 3; ++p) {
                float rr = 0.f, ri = 0.f;
                #pragma unroll
                for (int q = 0; q < 3; ++q) {
                    float k = sK[(o*3+i2)*9 + p*3 + q];
                    rr += k * evr[q]; ri += k * evi[q];
                }
                mr += eur[p]*rr - eui[p]*ri;
                mi += eur[p]*ri + eui[p]*rr;
            }
            Mr[o][i2] = mr; Mi[o][i2] = mi;
        }
        float c0r = (Mr[1][1]*Mr[2][2]-Mi[1][1]*Mi[2][2]) - (Mr[1][2]*Mr[2][1]-Mi[1][2]*Mi[2][1]);
        float c0i = (Mr[1][1]*Mi[2][2]+Mi[1][1]*Mr[2][2]) - (Mr[1][2]*Mi[2][1]+Mi[1][2]*Mr[2][1]);
        float c1r = (Mr[1][0]*Mr[2][2]-Mi[1][0]*Mi[2][2]) - (Mr[1][2]*Mr[2][0]-Mi[1][2]*Mi[2][0]);
        float c1i = (Mr[1][0]*Mi[2][2]+Mi[1][0]*Mr[2][2]) - (Mr[1][2]*Mi[2][0]+Mi[1][2]*Mr[2][0]);
        float c2r = (Mr[1][0]*Mr[2][1]-Mi[1][0]*Mi[2][1]) - (Mr[1][1]*Mr[2][0]-Mi[1][1]*Mi[2][0]);
        float c2i = (Mr[1][0]*Mi[2][1]+Mi[1][0]*Mr[2][1]) - (Mr[1][1]*Mi[2][0]+Mi[1][1]*Mr[2][0]);
        float dr = (Mr[0][0]*c0r-Mi[0][0]*c0i) - (Mr[0][1]*c1r-Mi[0][1]*c1i) + (Mr[0][2]*c2r-Mi[0][2]*c2i);
        float di = (Mr[0][0]*c0i+Mi[0][0]*c0r) - (Mr[0][1]*c1i+Mi[0][1]*c1r) + (Mr[0][2]*c2i+Mi[0][2]*c2r);
        part += 0.5f * __logf(dr*dr + di*di);
    }
    if (blockIdx.x == 0 && t == 0) {
        float s9 = 0.f;
        for (int i = 0; i < 9; ++i) s9 += als[i];
        part += 16384.f * s9;
    }
    #pragma unroll
    for (int o = 32; o > 0; o >>= 1) part += __shfl_down(part, o, 64);
    if ((t & 63) == 0) red[t >> 6] = part;
    __syncthreads();
    if (t == 0) atomicAdd(&ws[WS_LDCONST], red[0]+red[1]+red[2]+red[3]);
}

// ---------------- kernel 3: fused 3-layer main pass ------------------------
template<int S, bool FINAL>
static __device__ __forceinline__ void stage_fn(
    const float* src, float* dst,
    const float* ws,
    const float* __restrict__ cls, const float* __restrict__ cbias,
    int y0, int x0, float& ldpos, float* __restrict__ outb)
{
    constexpr int LI = S - 1;
    constexpr int W  = HB - 2*S;         // valid span this stage (36,34,32)
    constexpr int QX = (W + 3) / 4;      // pixel quads per row (9,9,8)
    constexpr int Q  = W * QX;
    for (int q = threadIdx.x; q < Q; q += 256) {
        int iy  = S + q / QX;
        int ix0 = S + 4 * (q - (q / QX) * QX);
        float acc[3][4];
        #pragma unroll
        for (int oc = 0; oc < 3; ++oc) {
            float cc = ws[WS_CC + LI*3 + oc];
            acc[oc][0] = cc; acc[oc][1] = cc; acc[oc][2] = cc; acc[oc][3] = cc;
        }
        #pragma unroll
        for (int ic = 0; ic < 3; ++ic) {
            #pragma unroll
            for (int dy = 0; dy < 3; ++dy) {
                const float* rp = src + (ic*HB + iy - 1 + dy)*WB + ix0 - 1;
                float r[6];
                #pragma unroll
                for (int k = 0; k < 6; ++k) r[k] = rp[k];
                #pragma unroll
                for (int oc = 0; oc < 3; ++oc) {
                    #pragma unroll
                    for (int dx = 0; dx < 3; ++dx) {
                        float w = ws[WS_W + ((LI*3+oc)*3 + ic)*9 + dy*3 + dx];
                        #pragma unroll
                        for (int j = 0; j < 4; ++j) acc[oc][j] = fmaf(w, r[dx + j], acc[oc][j]);
                    }
                }
            }
        }
        int gy = (y0 + iy - 3) & 127;
        bool rowin = (iy >= 3 && iy < 35);
        #pragma unroll
        for (int oc = 0; oc < 3; ++oc) {
            float a  = ws[WS_ALPHA  + LI*3 + oc];
            float ia = ws[WS_IALPHA + LI*3 + oc];
            const float* clsp = cls   + ((((LI*3 + oc) << 7) + gy) << 7);
            const float* cbp  = cbias + ((((LI*3 + oc) << 7) + gy) << 7);
            float hv[4];
            #pragma unroll
            for (int j = 0; j < 4; ++j) {
                int ixc = ix0 + j;
                int gx = (x0 + ixc - 3) & 127;
                float e  = __expf(clsp[gx]);
                float tv = fmaf(e, acc[oc][j], cbp[gx]);
                float at = a * fabsf(tv);
                float h  = copysignf(__logf(1.f + at) * ia, tv);
                hv[j] = h;
                bool in = FINAL || (rowin && ixc >= 3 && ixc < 35);
                if (in) ldpos += a * fabsf(h);
            }
            if constexpr (FINAL) {
                int gyo = y0 + iy - 3, gxo = x0 + ix0 - 3;
                float4 pk;
                pk.x = hv[0]; pk.y = hv[1]; pk.z = hv[2]; pk.w = hv[3];
                *reinterpret_cast<float4*>(outb + ((oc << 14) + (gyo << 7) + gxo)) = pk;
            } else {
                float* dp = dst + (oc*HB + iy)*WB + ix0;
                dp[0] = hv[0]; dp[1] = hv[1]; dp[2] = hv[2]; dp[3] = hv[3];
            }
        }
    }
}

__global__ __launch_bounds__(256, 4)
void k_main(const float* __restrict__ x,
            const float* __restrict__ cls,
            const float* __restrict__ cbias,
            const float* ws,
            float* ldacc,
            float* __restrict__ outh)
{
    __shared__ float Sb[2][BUFSZ];
    __shared__ float red[4];
    int t = threadIdx.x;
    int b    = blockIdx.x >> 4;
    int tile = blockIdx.x & 15;
    int y0 = (tile >> 2) << 5, x0 = (tile & 3) << 5;

    // zero both ping-pong buffers: every halo/pad read is finite by construction
    for (int i = t; i < 2*BUFSZ; i += 256) Sb[0][i] = 0.f;
    __syncthreads();

    // stage 0: load 38x38x3 halo tile (wrapped)
    const float* xb = x + (size_t)b * 49152;
    for (int i = t; i < C_*HB*HB; i += 256) {
        int c = i / (HB*HB); int r = i - c*(HB*HB); int iy = r / HB; int ix = r - iy*HB;
        int gy = (y0 + iy - 3) & 127, gx = (x0 + ix - 3) & 127;
        Sb[0][(c*HB + iy)*WB + ix] = xb[c*16384 + (gy << 7) + gx];
    }
    __syncthreads();
    float ldpos = 0.f;
    stage_fn<1, false>(Sb[0], Sb[1], ws, cls, cbias, y0, x0, ldpos, nullptr);
    __syncthreads();
    stage_fn<2, false>(Sb[1], Sb[0], ws, cls, cbias, y0, x0, ldpos, nullptr);
    __syncthreads();
    stage_fn<3, true >(Sb[0], nullptr, ws, cls, cbias, y0, x0, ldpos,
                       outh + (size_t)b * 49152);
    #pragma unroll
    for (int o = 32; o > 0; o >>= 1) ldpos += __shfl_down(ldpos, o, 64);
    if ((t & 63) == 0) red[t >> 6] = ldpos;
    __syncthreads();
    if (t == 0) atomicAdd(&ldacc[b], -(red[0] + red[1] + red[2] + red[3]));
}

// ---------------- kernel 4: finalize logdet --------------------------------
__global__ void k_fin(const float* __restrict__ ws, float* __restrict__ outld, int B)
{
    int b = blockIdx.x * 256 + threadIdx.x;
    if (b < B) outld[b] = ws[WS_LDCONST] + ws[WS_LDACC + b];
}

extern "C" void kernel_launch(void* const* d_in, const int* in_sizes, int n_in,
                              void* d_out, int out_size, void* d_ws, size_t ws_size,
                              hipStream_t stream)
{
    const float* x   = (const float*)d_in[0];
    const float* ab  = (const float*)d_in[1];
    const float* als = (const float*)d_in[2];
    const float* K   = (const float*)d_in[3];
    const float* cb  = (const float*)d_in[4];
    const float* cls = (const float*)d_in[5];
    const float* la  = (const float*)d_in[6];
    float* ws = (float*)d_ws;
    float* outh = (float*)d_out;                      // fp32: reference output dtype

    const int B = in_sizes[0] / 49152;                // batch from actual input size
    float* outld = outh + (size_t)B * 49152;

    k_init  <<<1,              1024, 0, stream>>>(ab, als, K, la, ws, B);
    k_logdet<<<48,             256,  0, stream>>>(als, K, cls, ws);
    k_main  <<<B * 16,         256,  0, stream>>>(x, cls, cb, ws, ws + WS_LDACC, outh);
    k_fin   <<<(B + 255)/256,  256,  0, stream>>>(ws, outld, B);
}

// Round 6
// 354.614 us; speedup vs baseline: 1.1063x; 1.1063x over previous
//
#include <hip/hip_runtime.h>

#define C_ 3
#define L_ 3
#define HB 38          // staged buffer rows/cols (32 + 2*3 halo)
#define WB 43          // padded LDS row stride (odd -> bank spread)
#define BUFSZ (C_*HB*WB)
#define NT   384       // threads/block in k_main (6 waves)

// ws layout (float indices)
#define WS_LDCONST 0
#define WS_W       8      // 243 folded conv weights
#define WS_CC      256    // 9 folded bias constants
#define WS_ALPHA   272    // 9
#define WS_IALPHA  288    // 9
#define WS_LDACC   2048   // B per-batch accumulators
#define WS_TAB     8192   // 147456 float2 = (alpha*exp(cls), alpha*cbias)

// ---------------- kernel 1: zero accumulators, fold weights ----------------
__global__ void k_init(const float* __restrict__ ab,   // actnorm_bias (L,1,C,1,1)
                       const float* __restrict__ als,  // actnorm_log_scale
                       const float* __restrict__ K,    // (L,C,C,3,3)
                       const float* __restrict__ la,   // slog_log_alpha
                       float* __restrict__ ws, int B)
{
    int t = threadIdx.x;
    if (t < 8) ws[t] = 0.f;
    for (int i = t; i < B; i += 1024) ws[WS_LDACC + i] = 0.f;
    if (t < 243) {
        int li = t / 81; int rem = t % 81; int ic = (rem % 27) / 9;
        // conv(actnorm(h)) fold: W' = K * exp(ls_ic)
        ws[WS_W + t] = K[t] * __expf(als[li*3 + ic]);
    }
    if (t >= 256 && t < 265) {
        int i = t - 256; int li = i / 3, oc = i % 3;
        float s = 0.f;
        for (int ic = 0; ic < 3; ++ic) {
            float ks = 0.f;
            for (int k9 = 0; k9 < 9; ++k9) ks += K[((li*3+oc)*3+ic)*9 + k9];
            s += ab[li*3 + ic] * ks;
        }
        ws[WS_CC + i] = s;
    }
    if (t >= 272 && t < 281) {
        int i = t - 272;
        float a = __expf(la[i]);
        ws[WS_ALPHA + i]  = a;
        ws[WS_IALPHA + i] = 1.f / a;
    }
}

// ------------- kernel 1b: fused epilogue table -----------------------------
// tab[ch][y][x] = (alpha_ch * exp(cls[ch][y][x]), alpha_ch * cbias[ch][y][x])
__global__ void k_tab(const float* __restrict__ cls, const float* __restrict__ cb,
                      const float* __restrict__ ws, float2* __restrict__ tab)
{
    int i = blockIdx.x * 256 + threadIdx.x;
    if (i < L_*C_*16384) {
        int ch = i >> 14;
        float a = ws[WS_ALPHA + ch];
        tab[i] = make_float2(a * __expf(cls[i]), a * cb[i]);
    }
}

// ------------- kernel 2: data-independent logdet constant ------------------
__global__ void k_logdet(const float* __restrict__ als,
                         const float* __restrict__ K,
                         const float* __restrict__ cls, // (L,1,C,N,N)
                         float* __restrict__ ws)
{
    __shared__ float sK[81];
    __shared__ float red[4];
    int li  = blockIdx.x >> 4;
    int sub = blockIdx.x & 15;
    int t = threadIdx.x;
    if (t < 81) sK[t] = K[li*81 + t];
    __syncthreads();
    float part = 0.f;
    {   // slice of sum(cls)
        const float* p = cls + li*(3*128*128) + sub*3072;
        for (int i = t; i < 3072; i += 256) part += p[i];
    }
    const float w0 = -(2.f * 3.14159265358979f / 128.f);
    for (int f = sub*1024 + t; f < sub*1024 + 1024; f += 256) {
        int u = f >> 7, v = f & 127;
        float su, cu, sv, cv;
        __sincosf(w0 * (float)u, &su, &cu);
        __sincosf(w0 * (float)v, &sv, &cv);
        float cu2 = cu*cu - su*su, su2 = 2.f*cu*su;
        float cv2 = cv*cv - sv*sv, sv2 = 2.f*cv*sv;
        float evr[3] = {1.f, cv, cv2}, evi[3] = {0.f, sv, sv2};
        float eur[3] = {1.f, cu, cu2}, eui[3] = {0.f, su, su2};
        float Mr[3][3], Mi[3][3];
        #pragma unroll
        for (int o = 0; o < 3; ++o)
        #pragma unroll
        for (int i2 = 0; i2 < 3; ++i2) {
            float mr = 0.f, mi = 0.f;
            #pragma unroll
            for (int p = 0; p < 3; ++p) {
                float rr = 0.f, ri = 0.f;
                #pragma unroll
                for (int q = 0; q < 3; ++q) {
                    float k = sK[(o*3+i2)*9 + p*3 + q];
                    rr += k * evr[q]; ri += k * evi[q];
                }
                mr += eur[p]*rr - eui[p]*ri;
                mi += eur[p]*ri + eui[p]*rr;
            }
            Mr[o][i2] = mr; Mi[o][i2] = mi;
        }
        float c0r = (Mr[1][1]*Mr[2][2]-Mi[1][1]*Mi[2][2]) - (Mr[1][2]*Mr[2][1]-Mi[1][2]*Mi[2][1]);
        float c0i = (Mr[1][1]*Mi[2][2]+Mi[1][1]*Mr[2][2]) - (Mr[1][2]*Mi[2][1]+Mi[1][2]*Mr[2][1]);
        float c1r = (Mr[1][0]*Mr[2][2]-Mi[1][0]*Mi[2][2]) - (Mr[1][2]*Mr[2][0]-Mi[1][2]*Mi[2][0]);
        float c1i = (Mr[1][0]*Mi[2][2]+Mi[1][0]*Mr[2][2]) - (Mr[1][2]*Mi[2][0]+Mi[1][2]*Mr[2][0]);
        float c2r = (Mr[1][0]*Mr[2][1]-Mi[1][0]*Mi[2][1]) - (Mr[1][1]*Mr[2][0]-Mi[1][1]*Mi[2][0]);
        float c2i = (Mr[1][0]*Mi[2][1]+Mi[1][0]*Mr[2][1]) - (Mr[1][1]*Mi[2][0]+Mi[1][1]*Mr[2][0]);
        float dr = (Mr[0][0]*c0r-Mi[0][0]*c0i) - (Mr[0][1]*c1r-Mi[0][1]*c1i) + (Mr[0][2]*c2r-Mi[0][2]*c2i);
        float di = (Mr[0][0]*c0i+Mi[0][0]*c0r) - (Mr[0][1]*c1i+Mi[0][1]*c1r) + (Mr[0][2]*c2i+Mi[0][2]*c2r);
        part += 0.5f * __logf(dr*dr + di*di);
    }
    if (blockIdx.x == 0 && t == 0) {
        float s9 = 0.f;
        for (int i = 0; i < 9; ++i) s9 += als[i];
        part += 16384.f * s9;
    }
    #pragma unroll
    for (int o = 32; o > 0; o >>= 1) part += __shfl_down(part, o, 64);
    if ((t & 63) == 0) red[t >> 6] = part;
    __syncthreads();
    if (t == 0) atomicAdd(&ws[WS_LDCONST], red[0]+red[1]+red[2]+red[3]);
}

// ---------------- kernel 3: fused 3-layer main pass ------------------------
template<int S, bool FINAL>
static __device__ __forceinline__ void stage_fn(
    const float* src, float* dst,
    const float* __restrict__ ws, const float2* __restrict__ tab,
    int y0, int x0, float& ldpos, float* __restrict__ outb)
{
    constexpr int LI = S - 1;
    constexpr int W  = HB - 2*S;         // valid span this stage (36,34,32)
    constexpr int QX = (W + 3) / 4;      // pixel quads per row (9,9,8)
    constexpr int Q  = W * QX;
    for (int q = threadIdx.x; q < Q; q += NT) {
        int iy  = S + q / QX;
        int ix0 = S + 4 * (q - (q / QX) * QX);
        float acc[3][4];
        #pragma unroll
        for (int oc = 0; oc < 3; ++oc) {
            float cc = ws[WS_CC + LI*3 + oc];
            acc[oc][0] = cc; acc[oc][1] = cc; acc[oc][2] = cc; acc[oc][3] = cc;
        }
        #pragma unroll
        for (int ic = 0; ic < 3; ++ic) {
            #pragma unroll
            for (int dy = 0; dy < 3; ++dy) {
                const float* rp = src + (ic*HB + iy - 1 + dy)*WB + ix0 - 1;
                float r[6];
                #pragma unroll
                for (int k = 0; k < 6; ++k) r[k] = rp[k];
                #pragma unroll
                for (int oc = 0; oc < 3; ++oc) {
                    #pragma unroll
                    for (int dx = 0; dx < 3; ++dx) {
                        float w = ws[WS_W + ((LI*3+oc)*3 + ic)*9 + dy*3 + dx];
                        #pragma unroll
                        for (int j = 0; j < 4; ++j) acc[oc][j] = fmaf(w, r[dx + j], acc[oc][j]);
                    }
                }
            }
        }
        int gy = (y0 + iy - 3) & 127;
        bool rowin = (iy >= 3 && iy < 35);
        #pragma unroll
        for (int oc = 0; oc < 3; ++oc) {
            float ia = ws[WS_IALPHA + LI*3 + oc];
            const float2* tp = tab + (((LI*3 + oc) << 14) + (gy << 7));
            float hv[4];
            #pragma unroll
            for (int j = 0; j < 4; ++j) {
                int ixc = ix0 + j;
                int gx = (x0 + ixc - 3) & 127;
                float2 tc = tp[gx];
                float u  = fmaf(tc.x, acc[oc][j], tc.y);      // = alpha * tv
                float lg = __logf(1.f + fabsf(u));            // = alpha*|h| = log1p(alpha|tv|)
                hv[j] = copysignf(lg * ia, u);
                bool in = FINAL || (rowin && ixc >= 3 && ixc < 35);
                if (in) ldpos += lg;
            }
            if constexpr (FINAL) {
                int gyo = y0 + iy - 3, gxo = x0 + ix0 - 3;
                float4 pk;
                pk.x = hv[0]; pk.y = hv[1]; pk.z = hv[2]; pk.w = hv[3];
                *reinterpret_cast<float4*>(outb + ((oc << 14) + (gyo << 7) + gxo)) = pk;
            } else {
                float* dp = dst + (oc*HB + iy)*WB + ix0;
                dp[0] = hv[0]; dp[1] = hv[1]; dp[2] = hv[2]; dp[3] = hv[3];
            }
        }
    }
}

__global__ __launch_bounds__(NT, 6)
void k_main(const float* __restrict__ x,
            const float* __restrict__ ws,
            const float2* __restrict__ tab,
            float* ldacc,
            float* __restrict__ outh)
{
    __shared__ float Sb[2][BUFSZ];
    __shared__ float red[NT/64];
    int t = threadIdx.x;
    int b    = blockIdx.x >> 4;
    int tile = blockIdx.x & 15;
    int y0 = (tile >> 2) << 5, x0 = (tile & 3) << 5;

    // zero only pad columns 36..42 (the only cells ever read before written);
    // buffers are contiguous: 2*3*38 = 228 rows of WB
    for (int i = t; i < 228*7; i += NT) {
        int seg = i / 7, col = 36 + (i - seg*7);
        Sb[0][seg*WB + col] = 0.f;
    }

    // stage 0: load 38x38x3 halo tile (wrapped)
    const float* xb = x + (size_t)b * 49152;
    for (int i = t; i < C_*HB*HB; i += NT) {
        int c = i / (HB*HB); int r = i - c*(HB*HB); int iy = r / HB; int ix = r - iy*HB;
        int gy = (y0 + iy - 3) & 127, gx = (x0 + ix - 3) & 127;
        Sb[0][(c*HB + iy)*WB + ix] = xb[c*16384 + (gy << 7) + gx];
    }
    __syncthreads();
    float ldpos = 0.f;
    stage_fn<1, false>(Sb[0], Sb[1], ws, tab, y0, x0, ldpos, nullptr);
    __syncthreads();
    stage_fn<2, false>(Sb[1], Sb[0], ws, tab, y0, x0, ldpos, nullptr);
    __syncthreads();
    stage_fn<3, true >(Sb[0], nullptr, ws, tab, y0, x0, ldpos,
                       outh + (size_t)b * 49152);
    #pragma unroll
    for (int o = 32; o > 0; o >>= 1) ldpos += __shfl_down(ldpos, o, 64);
    if ((t & 63) == 0) red[t >> 6] = ldpos;
    __syncthreads();
    if (t == 0) {
        float s = 0.f;
        #pragma unroll
        for (int wv = 0; wv < NT/64; ++wv) s += red[wv];
        atomicAdd(&ldacc[b], -s);
    }
}

// ---------------- kernel 4: finalize logdet --------------------------------
__global__ void k_fin(const float* __restrict__ ws, float* __restrict__ outld, int B)
{
    int b = blockIdx.x * 256 + threadIdx.x;
    if (b < B) outld[b] = ws[WS_LDCONST] + ws[WS_LDACC + b];
}

extern "C" void kernel_launch(void* const* d_in, const int* in_sizes, int n_in,
                              void* d_out, int out_size, void* d_ws, size_t ws_size,
                              hipStream_t stream)
{
    const float* x   = (const float*)d_in[0];
    const float* ab  = (const float*)d_in[1];
    const float* als = (const float*)d_in[2];
    const float* K   = (const float*)d_in[3];
    const float* cb  = (const float*)d_in[4];
    const float* cls = (const float*)d_in[5];
    const float* la  = (const float*)d_in[6];
    float* ws = (float*)d_ws;
    float* outh = (float*)d_out;                      // fp32: reference output dtype
    float2* tab = (float2*)(ws + WS_TAB);

    const int B = in_sizes[0] / 49152;                // batch from actual input size
    float* outld = outh + (size_t)B * 49152;

    k_init  <<<1,              1024, 0, stream>>>(ab, als, K, la, ws, B);
    k_tab   <<<576,            256,  0, stream>>>(cls, cb, ws, tab);
    k_logdet<<<48,             256,  0, stream>>>(als, K, cls, ws);
    k_main  <<<B * 16,         NT,   0, stream>>>(x, ws, tab, ws + WS_LDACC, outh);
    k_fin   <<<(B + 255)/256,  256,  0, stream>>>(ws, outld, B);
}